// Round 3
// baseline (179.712 us; speedup 1.0000x reference)
//
#include <hip/hip_runtime.h>
#include <stdint.h>

typedef __attribute__((ext_vector_type(8))) short bf16x8;
typedef __attribute__((ext_vector_type(4))) float f32x4;
typedef unsigned short ushort_t;

__device__ __forceinline__ unsigned short f2bf(float f){
  union { float f; unsigned u; } c; c.f = f;
  unsigned u = c.u;
  u = u + 0x7FFFu + ((u >> 16) & 1u);
  return (unsigned short)(u >> 16);
}

__device__ __forceinline__ bf16x8 cvt8(const float* p){
  const float4 a = ((const float4*)p)[0];
  const float4 b = ((const float4*)p)[1];
  bf16x8 r;
  r[0]=(short)f2bf(a.x); r[1]=(short)f2bf(a.y); r[2]=(short)f2bf(a.z); r[3]=(short)f2bf(a.w);
  r[4]=(short)f2bf(b.x); r[5]=(short)f2bf(b.y); r[6]=(short)f2bf(b.z); r[7]=(short)f2bf(b.w);
  return r;
}

__device__ __forceinline__ uint32_t pk2bf(float a, float b){
  uint32_t r;
  asm("v_cvt_pk_bf16_f32 %0, %1, %2" : "=v"(r) : "v"(a), "v"(b));
  return r;
}

__device__ __forceinline__ float exp2x(float x){
  float r;
  asm("v_exp_f32 %0, %1" : "=v"(r) : "v"(x));
  return r;
}

// ---------------- Kernel 0: weight pre-convert f32 -> bf16 ----------------
// out layout: [4][7*64*64] bf16; Wq (a==0) pre-scaled by log2(e)/sqrt(96).
__global__ __launch_bounds__(256) void wconv(
    const float* __restrict__ Wq, const float* __restrict__ Wk,
    const float* __restrict__ Wv, const float* __restrict__ Wo,
    ushort_t* __restrict__ out)
{
  const int a = blockIdx.y;
  const float* src = (a==0)?Wq:(a==1)?Wk:(a==2)?Wv:Wo;
  const float sc = (a==0) ? 0.14724743479535623f : 1.0f;
  const int i = (blockIdx.x*256 + threadIdx.x)*8;   // 14*256*8 = 28672
  float4 v0 = *(const float4*)(src+i);
  float4 v1 = *(const float4*)(src+i+4);
  uint4 o;
  o.x = pk2bf(v0.x*sc, v0.y*sc);
  o.y = pk2bf(v0.z*sc, v0.w*sc);
  o.z = pk2bf(v1.x*sc, v1.y*sc);
  o.w = pk2bf(v1.z*sc, v1.w*sc);
  *(uint4*)(out + (size_t)a*28672 + i) = o;
}

// ---------------- Kernel A: QKV projection ----------------
// Per key i: C[rows,64] = X_i[rows,64] @ W[i]^T. Store bf16 [B,S,12,64] (inner o = h*8+mm).
__global__ __launch_bounds__(256) void qkv_proj(
    const float* __restrict__ xA1, const float* __restrict__ xB2,
    const float* __restrict__ xE1, const float* __restrict__ xE2,
    const float* __restrict__ xE3, const float* __restrict__ xE4,
    const float* __restrict__ xE5,
    const ushort_t* __restrict__ Wb4,     // [4][7*64*64] bf16 (q,k,v,o)
    ushort_t* __restrict__ Qb, ushort_t* __restrict__ Kb,
    ushort_t* __restrict__ Vb)
{
  const int dims[7] = {1,1,2,2,2,2,2};
  const int rrb_[7] = {0,1,2,4,6,8,10};
  const int tile = blockIdx.x;           // 0..1535
  int i = 0, t0 = 0;
  for (int k = 0; k < 7; ++k){
    int n = 128 * dims[k];
    if (tile >= t0 + n) t0 += n; else { i = k; break; }
  }
  const int d = dims[i], rrb = rrb_[i];
  const float* xp = (i==0)?xA1:(i==1)?xB2:(i==2)?xE1:(i==3)?xE2:(i==4)?xE3:(i==5)?xE4:xE5;

  const int lane = threadIdx.x & 63;
  const int w    = threadIdx.x >> 6;
  const int lo = lane & 15, hi = lane >> 4;
  const int row0 = (tile - t0) * 64 + w * 16;

  bf16x8 afr[2];
  {
    const float* rp = xp + (size_t)(row0 + lo) * 64;
    afr[0] = cvt8(rp + 8*hi);
    afr[1] = cvt8(rp + 32 + 8*hi);
  }

  ushort_t* Ob[3] = {Qb, Kb, Vb};

  #pragma unroll
  for (int wsel = 0; wsel < 3; ++wsel){
    const ushort_t* Wb = Wb4 + (size_t)wsel*28672 + (size_t)i * 64 * 64;
    #pragma unroll
    for (int ot = 0; ot < 4; ++ot){
      f32x4 acc = {0.f,0.f,0.f,0.f};
      #pragma unroll
      for (int c = 0; c < 2; ++c){
        bf16x8 bfr = *(const bf16x8*)(Wb + (size_t)(lo + 16*ot) * 64 + 32*c + 8*hi);
        acc = __builtin_amdgcn_mfma_f32_16x16x32_bf16(afr[c], bfr, acc, 0, 0, 0);
      }
      const int o = lo + 16*ot;
      #pragma unroll
      for (int r = 0; r < 4; ++r){
        int R  = row0 + hi*4 + r;
        int bs = (d == 2) ? (R >> 1) : R;
        int dx = (d == 2) ? (R & 1)  : 0;
        Ob[wsel][(size_t)(bs*12 + rrb + dx) * 64 + o] = f2bf(acc[r]);
      }
    }
  }
}

// ---------------- Kernel B: flash attention (swapped QK^T, O^T accum) ----------------
// grid 1024: bid -> (bh, qt) XCD-swizzled. 4 waves x 16 q-rows. KV tiles of 64.
__global__ __launch_bounds__(256, 4) void attn(
    const ushort_t* __restrict__ Qb,
    const ushort_t* __restrict__ Kb,
    const ushort_t* __restrict__ Vb,
    ushort_t* __restrict__ Oc)
{
  __shared__ short    Kl[64*104];        // K tile [64 kv][96 f], pad 104          (13312 B)
  __shared__ short    Vt[96*72];         // V^T [96 f][64 kv + pad], col swz kv^8*(rr&3) (13824 B)
  __shared__ uint32_t Pl[4][16*36];      // per-wave P packed [16 q][32 W], pad 36  (9216 B)

  const int bid = blockIdx.x;
  const int xcd = bid & 7, u = bid >> 3;       // u: 0..127
  const int bh = xcd*8 + (u & 7);
  const int qt = u >> 3;                       // 0..15
  const int b = bh >> 3, h = bh & 7;
  const int w = threadIdx.x >> 6, lane = threadIdx.x & 63;
  const int lo = lane & 15, hi = lane >> 4;
  const int q0 = qt*64 + w*16;

  // Q fragments (B-operand): lane holds Q[q0+lo][32c+8hi+j]
  bf16x8 qf[3];
  #pragma unroll
  for (int c = 0; c < 3; ++c)
    qf[c] = *(const bf16x8*)(Qb + ((size_t)(b*1024 + q0 + lo)*12 + (4*c+hi))*64 + h*8);

  f32x4 acc[6];
  #pragma unroll
  for (int ft = 0; ft < 6; ++ft) acc[ft] = (f32x4){0,0,0,0};
  float mr = -1e30f, lr = 0.f;

  // staging: tid = skv*4 + ss; unit i: rr = 3*ss+i (3 K + 3 V uint4 per thread)
  const int skv = threadIdx.x >> 2;
  const int ss  = threadIdx.x & 3;
  uint4 pk[3], pv[3];

  #pragma unroll
  for (int i = 0; i < 3; ++i){
    int rr = 3*ss + i;
    size_t gb = ((size_t)(b*1024 + skv)*12 + rr)*64 + h*8;
    pk[i] = *(const uint4*)(Kb + gb);
    pv[i] = *(const uint4*)(Vb + gb);
  }
  #pragma unroll
  for (int i = 0; i < 3; ++i){
    int rr = 3*ss + i;
    *(uint4*)&Kl[skv*104 + rr*8] = pk[i];
    const ushort_t* vs = (const ushort_t*)&pv[i];
    int swz = (rr & 3) * 8;
    #pragma unroll
    for (int j = 0; j < 8; ++j) Vt[(rr*8+j)*72 + (skv ^ swz)] = vs[j];
  }
  __syncthreads();

  for (int t = 0; t < 16; ++t){
    if (t < 15){
      int kv0 = (t+1)*64;
      #pragma unroll
      for (int i = 0; i < 3; ++i){
        int rr = 3*ss + i;
        size_t gb = ((size_t)(b*1024 + kv0 + skv)*12 + rr)*64 + h*8;
        pk[i] = *(const uint4*)(Kb + gb);
        pv[i] = *(const uint4*)(Vb + gb);
      }
    }

    // QK^T (swapped): S^T[kv][q]
    f32x4 st[4];
    #pragma unroll
    for (int kvb = 0; kvb < 4; ++kvb){
      f32x4 s = {0.f,0.f,0.f,0.f};
      #pragma unroll
      for (int c = 0; c < 3; ++c){
        bf16x8 kf = *(const bf16x8*)&Kl[(kvb*16 + lo)*104 + (4*c+hi)*8];
        s = __builtin_amdgcn_mfma_f32_16x16x32_bf16(kf, qf[c], s, 0, 0, 0);
      }
      st[kvb] = s;
    }

    // online softmax; lane owns q-row lo, 16 kv logits in regs
    float tm = st[0][0];
    #pragma unroll
    for (int kvb = 0; kvb < 4; ++kvb)
      #pragma unroll
      for (int r = 0; r < 4; ++r) tm = fmaxf(tm, st[kvb][r]);
    tm = fmaxf(tm, __shfl_xor(tm, 16));
    tm = fmaxf(tm, __shfl_xor(tm, 32));
    if (!__all(tm - mr <= 8.f)){
      float mn = fmaxf(mr, tm);
      float al = exp2x(mr - mn);
      lr *= al;
      #pragma unroll
      for (int ft = 0; ft < 6; ++ft)
        #pragma unroll
        for (int r = 0; r < 4; ++r) acc[ft][r] *= al;
      mr = mn;
    }
    float ps = 0.f;
    #pragma unroll
    for (int kvb = 0; kvb < 4; ++kvb)
      #pragma unroll
      for (int r = 0; r < 4; ++r){ st[kvb][r] = exp2x(st[kvb][r] - mr); ps += st[kvb][r]; }
    ps += __shfl_xor(ps, 16);
    ps += __shfl_xor(ps, 32);
    lr += ps;
    #pragma unroll
    for (int kvb = 0; kvb < 4; ++kvb)
      #pragma unroll
      for (int c = 0; c < 2; ++c)
        Pl[w][lo*36 + kvb*8 + 2*hi + c] = pk2bf(st[kvb][2*c], st[kvb][2*c+1]);

    // PV: O^T[f][q] += V^T-frag x P^T-frag
    #pragma unroll
    for (int ch = 0; ch < 2; ++ch){
      bf16x8 pb = *(const bf16x8*)&Pl[w][lo*36 + ch*16 + 4*hi];
      #pragma unroll
      for (int ft = 0; ft < 6; ++ft){
        int f = ft*16 + lo;
        int swz = ((f >> 3) & 3) * 8;
        bf16x8 va = *(const bf16x8*)&Vt[f*72 + ((ch*32 + 8*hi) ^ swz)];
        acc[ft] = __builtin_amdgcn_mfma_f32_16x16x32_bf16(va, pb, acc[ft], 0, 0, 0);
      }
    }

    __syncthreads();
    if (t < 15){
      #pragma unroll
      for (int i = 0; i < 3; ++i){
        int rr = 3*ss + i;
        *(uint4*)&Kl[skv*104 + rr*8] = pk[i];
        const ushort_t* vs = (const ushort_t*)&pv[i];
        int swz = (rr & 3) * 8;
        #pragma unroll
        for (int j = 0; j < 8; ++j) Vt[(rr*8+j)*72 + (skv ^ swz)] = vs[j];
      }
    }
    __syncthreads();
  }

  // epilogue: O^T -> bf16 Oc [B,S,12,64] (inner = h*8+mm)
  float rl = 1.f / lr;
  #pragma unroll
  for (int ft = 0; ft < 6; ++ft){
    uint2 o;
    o.x = pk2bf(acc[ft][0]*rl, acc[ft][1]*rl);
    o.y = pk2bf(acc[ft][2]*rl, acc[ft][3]*rl);
    int f0 = ft*16 + 4*hi;
    int rr = f0 >> 3, mm0 = f0 & 7;
    size_t ad = ((size_t)(b*1024 + q0 + lo)*12 + rr)*64 + h*8 + mm0;
    *(uint2*)(Oc + ad) = o;
  }
}

// ---------------- Kernel C: output projection ----------------
__global__ __launch_bounds__(256) void out_proj(
    const ushort_t* __restrict__ Oc,
    const ushort_t* __restrict__ Wb4,
    float* __restrict__ out)
{
  const int dims[7] = {1,1,2,2,2,2,2};
  const int rrb_[7] = {0,1,2,4,6,8,10};
  const int tile = blockIdx.x;
  int i = 0, t0 = 0;
  for (int k = 0; k < 7; ++k){
    int n = 128 * dims[k];
    if (tile >= t0 + n) t0 += n; else { i = k; break; }
  }
  const int d = dims[i], rrb = rrb_[i];
  const int w = threadIdx.x >> 6, lane = threadIdx.x & 63;
  const int lo = lane & 15, hi = lane >> 4;
  const int row0 = (tile - t0) * 64 + w * 16;

  bf16x8 afr[2];
  {
    int R  = row0 + lo;
    int bs = (d == 2) ? (R >> 1) : R;
    int dx = (d == 2) ? (R & 1)  : 0;
    const ushort_t* rp = Oc + (size_t)(bs*12 + rrb + dx) * 64;
    afr[0] = *(const bf16x8*)(rp + 8*hi);
    afr[1] = *(const bf16x8*)(rp + 32 + 8*hi);
  }
  const ushort_t* Wb = Wb4 + (size_t)3*28672 + (size_t)i * 64 * 64;
  #pragma unroll
  for (int ot = 0; ot < 4; ++ot){
    f32x4 acc = {0.f,0.f,0.f,0.f};
    #pragma unroll
    for (int c = 0; c < 2; ++c){
      bf16x8 bfr = *(const bf16x8*)(Wb + (size_t)(lo + 16*ot) * 64 + 32*c + 8*hi);
      acc = __builtin_amdgcn_mfma_f32_16x16x32_bf16(afr[c], bfr, acc, 0, 0, 0);
    }
    #pragma unroll
    for (int r = 0; r < 4; ++r){
      int R  = row0 + hi*4 + r;
      int bs = (d == 2) ? (R >> 1) : R;
      int dx = (d == 2) ? (R & 1)  : 0;
      out[(size_t)(bs*12 + rrb + dx) * 64 + lo + 16*ot] = acc[r];
    }
  }
}

extern "C" void kernel_launch(void* const* d_in, const int* in_sizes, int n_in,
                              void* d_out, int out_size, void* d_ws, size_t ws_size,
                              hipStream_t stream)
{
  const float* xA1 = (const float*)d_in[0];
  const float* xB2 = (const float*)d_in[1];
  const float* xE1 = (const float*)d_in[2];
  const float* xE2 = (const float*)d_in[3];
  const float* xE3 = (const float*)d_in[4];
  const float* xE4 = (const float*)d_in[5];
  const float* xE5 = (const float*)d_in[6];
  const float* Wq  = (const float*)d_in[7];
  const float* Wk  = (const float*)d_in[8];
  const float* Wv  = (const float*)d_in[9];
  const float* Wo  = (const float*)d_in[10];

  const size_t NE = (size_t)8 * 1024 * 12 * 64;   // 6,291,456
  ushort_t* Qb = (ushort_t*)d_ws;
  ushort_t* Kb = Qb + NE;
  ushort_t* Vb = Kb + NE;
  ushort_t* Oc = Vb + NE;
  ushort_t* Wb4 = Oc + NE;                        // 4*28672 bf16

  wconv<<<dim3(14,4), dim3(256), 0, stream>>>(Wq, Wk, Wv, Wo, Wb4);
  qkv_proj<<<dim3(1536), dim3(256), 0, stream>>>(xA1,xB2,xE1,xE2,xE3,xE4,xE5,
                                                 Wb4, Qb,Kb,Vb);
  attn<<<dim3(1024), dim3(256), 0, stream>>>(Qb,Kb,Vb, Oc);
  out_proj<<<dim3(1536), dim3(256), 0, stream>>>(Oc, Wb4, (float*)d_out);
}

// Round 4
// 81.950 us; speedup vs baseline: 2.1929x; 2.1929x over previous
//
#include <hip/hip_runtime.h>
#include <stdint.h>

typedef __attribute__((ext_vector_type(8))) short bf16x8;
typedef __attribute__((ext_vector_type(4))) float f32x4;
typedef unsigned short ushort_t;

__device__ __forceinline__ unsigned short f2bf(float f){
  union { float f; unsigned u; } c; c.f = f;
  unsigned u = c.u;
  u = u + 0x7FFFu + ((u >> 16) & 1u);
  return (unsigned short)(u >> 16);
}

__device__ __forceinline__ bf16x8 cvt8(const float* p){
  const float4 a = ((const float4*)p)[0];
  const float4 b = ((const float4*)p)[1];
  bf16x8 r;
  r[0]=(short)f2bf(a.x); r[1]=(short)f2bf(a.y); r[2]=(short)f2bf(a.z); r[3]=(short)f2bf(a.w);
  r[4]=(short)f2bf(b.x); r[5]=(short)f2bf(b.y); r[6]=(short)f2bf(b.z); r[7]=(short)f2bf(b.w);
  return r;
}

__device__ __forceinline__ uint32_t pk2bf(float a, float b){
  uint32_t r;
  asm("v_cvt_pk_bf16_f32 %0, %1, %2" : "=v"(r) : "v"(a), "v"(b));
  return r;
}

__device__ __forceinline__ float exp2x(float x){
  float r;
  asm("v_exp_f32 %0, %1" : "=v"(r) : "v"(x));
  return r;
}

__device__ __forceinline__ void gll16(const ushort_t* g, short* l){
  __builtin_amdgcn_global_load_lds(
      (const __attribute__((address_space(1))) unsigned int*)g,
      (__attribute__((address_space(3))) unsigned int*)l, 16, 0, 0);
}

// ---------------- Kernel 0: weight pre-convert f32 -> bf16 ----------------
__global__ __launch_bounds__(256) void wconv(
    const float* __restrict__ Wq, const float* __restrict__ Wk,
    const float* __restrict__ Wv, const float* __restrict__ Wo,
    ushort_t* __restrict__ out)
{
  const int a = blockIdx.y;
  const float* src = (a==0)?Wq:(a==1)?Wk:(a==2)?Wv:Wo;
  const float sc = (a==0) ? 0.14724743479535623f : 1.0f;  // log2(e)/sqrt(96)
  const int i = (blockIdx.x*256 + threadIdx.x)*8;
  float4 v0 = *(const float4*)(src+i);
  float4 v1 = *(const float4*)(src+i+4);
  uint4 o;
  o.x = pk2bf(v0.x*sc, v0.y*sc);
  o.y = pk2bf(v0.z*sc, v0.w*sc);
  o.z = pk2bf(v1.x*sc, v1.y*sc);
  o.w = pk2bf(v1.z*sc, v1.w*sc);
  *(uint4*)(out + (size_t)a*28672 + i) = o;
}

// ---------------- Kernel A: QKV projection ----------------
// Stores Q/K/V in per-(b,h) MFMA-fragment order:
//  Q,K: addr = ((bh*16 + s>>6))*6144 + ((((s>>4)&3)*3 + rr>>2)*64 + (rr&3)*16 + (s&15))*8 + mm
//  V  : addr = ((bh*16 + s>>6))*6144 + (((s6>>5)*6 + f>>4)*64 + ((rem>>2)&3)*16 + (f&15))*8 + jj
//       where s6=s&63, rem=s6&31, jj=(rem&3)+4*(rem>>4), f = rr*8+mm   (pi-permuted kv slots)
__global__ __launch_bounds__(256) void qkv_proj(
    const float* __restrict__ xA1, const float* __restrict__ xB2,
    const float* __restrict__ xE1, const float* __restrict__ xE2,
    const float* __restrict__ xE3, const float* __restrict__ xE4,
    const float* __restrict__ xE5,
    const ushort_t* __restrict__ Wb4,
    ushort_t* __restrict__ Qg, ushort_t* __restrict__ Kg,
    ushort_t* __restrict__ Vg)
{
  const int dims[7] = {1,1,2,2,2,2,2};
  const int rrb_[7] = {0,1,2,4,6,8,10};
  const int tile = blockIdx.x;           // 0..1535
  int i = 0, t0 = 0;
  for (int k = 0; k < 7; ++k){
    int n = 128 * dims[k];
    if (tile >= t0 + n) t0 += n; else { i = k; break; }
  }
  const int d = dims[i], rrb = rrb_[i];
  const float* xp = (i==0)?xA1:(i==1)?xB2:(i==2)?xE1:(i==3)?xE2:(i==4)?xE3:(i==5)?xE4:xE5;

  const int lane = threadIdx.x & 63;
  const int w    = threadIdx.x >> 6;
  const int lo = lane & 15, hi = lane >> 4;
  const int row0 = (tile - t0) * 64 + w * 16;

  bf16x8 afr[2];
  {
    const float* rp = xp + (size_t)(row0 + lo) * 64;
    afr[0] = cvt8(rp + 8*hi);
    afr[1] = cvt8(rp + 32 + 8*hi);
  }

  ushort_t* Ob[3] = {Qg, Kg, Vg};

  #pragma unroll
  for (int wsel = 0; wsel < 3; ++wsel){
    const ushort_t* Wb = Wb4 + (size_t)wsel*28672 + (size_t)i * 64 * 64;
    #pragma unroll
    for (int ot = 0; ot < 4; ++ot){
      f32x4 acc = {0.f,0.f,0.f,0.f};
      #pragma unroll
      for (int c = 0; c < 2; ++c){
        bf16x8 bfr = *(const bf16x8*)(Wb + (size_t)(lo + 16*ot) * 64 + 32*c + 8*hi);
        acc = __builtin_amdgcn_mfma_f32_16x16x32_bf16(afr[c], bfr, acc, 0, 0, 0);
      }
      const int o  = lo + 16*ot;
      const int hh = o >> 3, mm = o & 7;
      #pragma unroll
      for (int r = 0; r < 4; ++r){
        int R  = row0 + hi*4 + r;
        int bs = (d == 2) ? (R >> 1) : R;
        int dx = (d == 2) ? (R & 1)  : 0;
        int bb = bs >> 10, s = bs & 1023;
        int rr = rrb + dx;
        size_t tb = (size_t)((bb*8 + hh)*16 + (s >> 6)) * 6144;
        unsigned short val = f2bf(acc[r]);
        if (wsel < 2){
          size_t a = tb + (size_t)(((((s>>4)&3)*3 + (rr>>2))*64 + (rr&3)*16 + (s&15)))*8 + mm;
          Ob[wsel][a] = val;
        } else {
          int s6 = s & 63, rem = s6 & 31;
          int jj = (rem & 3) + ((rem >> 4) << 2);
          int f  = rr*8 + mm;
          size_t a = tb + (size_t)((((s6>>5)*6 + (f>>4))*64 + ((rem>>2)&3)*16 + (f&15)))*8 + jj;
          Ob[2][a] = val;
        }
      }
    }
  }
}

// ---------------- Kernel B: flash attention ----------------
// grid 512: xcd = bid&7, bh = xcd*8 + ((bid>>3)&7), qt = bid>>6.
// 4 waves x 32 q-rows (g=2). KV tile 64, frag-order LDS, double-buffered via
// global_load_lds; one barrier per tile. P-transpose eliminated via pi-permuted
// kv slots baked into the V layout.
__global__ __launch_bounds__(256, 2) void attn(
    const ushort_t* __restrict__ Qg,
    const ushort_t* __restrict__ Kg,
    const ushort_t* __restrict__ Vg,
    ushort_t* __restrict__ Oc)
{
  __shared__ __align__(16) short Kl[2][6144];   // [buf][frag-order 64kv x 96f]
  __shared__ __align__(16) short Vl[2][6144];

  const int bid = blockIdx.x;
  const int bh = (bid & 7)*8 + ((bid >> 3) & 7);
  const int qt = bid >> 6;                      // 0..7 (q-tile of 128)
  const int b = bh >> 3, h = bh & 7;
  const int tid = threadIdx.x;
  const int w = tid >> 6, lane = tid & 63;
  const int lo = lane & 15, hi = lane >> 4;
  const size_t base = (size_t)bh * 16 * 6144;

  // Q fragments: frag-order load, lane-linear (coalesced)
  bf16x8 qf[2][3];
  #pragma unroll
  for (int g = 0; g < 2; ++g){
    int qq = qt*128 + w*32 + g*16;
    const ushort_t* qb = Qg + base + (size_t)(qq >> 6)*6144 + (size_t)(((qq>>4)&3)*3)*512;
    #pragma unroll
    for (int c = 0; c < 3; ++c)
      qf[g][c] = *(const bf16x8*)(qb + (c*64 + lane)*8);
  }

  f32x4 acc[6][2];
  #pragma unroll
  for (int ft = 0; ft < 6; ++ft){ acc[ft][0] = (f32x4){0,0,0,0}; acc[ft][1] = (f32x4){0,0,0,0}; }
  float mr[2] = {-1e30f, -1e30f}, lr[2] = {0.f, 0.f};

#define STAGE(tt, bb) do { \
    const ushort_t* kg_ = Kg + base + (size_t)(tt)*6144 + tid*8; \
    const ushort_t* vg_ = Vg + base + (size_t)(tt)*6144 + tid*8; \
    short* kl_ = &Kl[bb][tid*8]; short* vl_ = &Vl[bb][tid*8]; \
    gll16(kg_,        kl_);        gll16(kg_ + 2048, kl_ + 2048); \
    gll16(kg_ + 4096, kl_ + 4096); gll16(vg_,        vl_); \
    gll16(vg_ + 2048, vl_ + 2048); gll16(vg_ + 4096, vl_ + 4096); \
  } while(0)

  STAGE(0, 0);
  __syncthreads();

  for (int t = 0; t < 16; ++t){
    if (t < 15) STAGE(t+1, (t+1)&1);
    const int cb = t & 1;

    // QK^T (swapped): st[g][kvb][r] = S^T[kv=16kvb+4hi+r][q = q0+g*16+lo]
    f32x4 st[2][4];
    #pragma unroll
    for (int kvb = 0; kvb < 4; ++kvb){
      bf16x8 kf[3];
      #pragma unroll
      for (int c = 0; c < 3; ++c)
        kf[c] = *(const bf16x8*)&Kl[cb][((kvb*3 + c)*64 + lane)*8];
      #pragma unroll
      for (int g = 0; g < 2; ++g){
        f32x4 s = {0.f,0.f,0.f,0.f};
        #pragma unroll
        for (int c = 0; c < 3; ++c)
          s = __builtin_amdgcn_mfma_f32_16x16x32_bf16(kf[c], qf[g][c], s, 0, 0, 0);
        st[g][kvb] = s;
      }
    }

    // online softmax per g; then pack P words (zero cross-lane moves)
    bf16x8 pb[2][2];
    #pragma unroll
    for (int g = 0; g < 2; ++g){
      float tm = st[g][0][0];
      #pragma unroll
      for (int kvb = 0; kvb < 4; ++kvb)
        #pragma unroll
        for (int r = 0; r < 4; ++r) tm = fmaxf(tm, st[g][kvb][r]);
      tm = fmaxf(tm, __shfl_xor(tm, 16));
      tm = fmaxf(tm, __shfl_xor(tm, 32));
      if (!__all(tm - mr[g] <= 8.f)){
        float mn = fmaxf(mr[g], tm);
        float al = exp2x(mr[g] - mn);
        lr[g] *= al;
        #pragma unroll
        for (int ft = 0; ft < 6; ++ft)
          #pragma unroll
          for (int r = 0; r < 4; ++r) acc[ft][g][r] *= al;
        mr[g] = mn;
      }
      float ps = 0.f;
      #pragma unroll
      for (int kvb = 0; kvb < 4; ++kvb)
        #pragma unroll
        for (int r = 0; r < 4; ++r){ st[g][kvb][r] = exp2x(st[g][kvb][r] - mr[g]); ps += st[g][kvb][r]; }
      ps += __shfl_xor(ps, 16);
      ps += __shfl_xor(ps, 32);
      lr[g] += ps;
      #pragma unroll
      for (int ch = 0; ch < 2; ++ch){
        union { uint32_t u[4]; bf16x8 v; } pu;
        pu.u[0] = pk2bf(st[g][2*ch  ][0], st[g][2*ch  ][1]);
        pu.u[1] = pk2bf(st[g][2*ch  ][2], st[g][2*ch  ][3]);
        pu.u[2] = pk2bf(st[g][2*ch+1][0], st[g][2*ch+1][1]);
        pu.u[3] = pk2bf(st[g][2*ch+1][2], st[g][2*ch+1][3]);
        pb[g][ch] = pu.v;
      }
    }

    // PV: O^T[f][q] += V^T-frag (pi-order) x P-frag (own regs)
    #pragma unroll
    for (int ch = 0; ch < 2; ++ch){
      #pragma unroll
      for (int ft = 0; ft < 6; ++ft){
        bf16x8 va = *(const bf16x8*)&Vl[cb][((ch*6 + ft)*64 + lane)*8];
        acc[ft][0] = __builtin_amdgcn_mfma_f32_16x16x32_bf16(va, pb[0][ch], acc[ft][0], 0, 0, 0);
        acc[ft][1] = __builtin_amdgcn_mfma_f32_16x16x32_bf16(va, pb[1][ch], acc[ft][1], 0, 0, 0);
      }
    }

    __syncthreads();
  }
#undef STAGE

  // epilogue: O^T -> bf16 Oc [B,S,12,64] (inner = h*8+mm)
  #pragma unroll
  for (int g = 0; g < 2; ++g){
    float rl = 1.f / lr[g];
    int q = qt*128 + w*32 + g*16 + lo;
    #pragma unroll
    for (int ft = 0; ft < 6; ++ft){
      uint2 o;
      o.x = pk2bf(acc[ft][g][0]*rl, acc[ft][g][1]*rl);
      o.y = pk2bf(acc[ft][g][2]*rl, acc[ft][g][3]*rl);
      int f0 = ft*16 + 4*hi;
      int rr = f0 >> 3, mm0 = f0 & 7;
      size_t ad = ((size_t)(b*1024 + q)*12 + rr)*64 + h*8 + mm0;
      *(uint2*)(Oc + ad) = o;
    }
  }
}

// ---------------- Kernel C: output projection ----------------
__global__ __launch_bounds__(256) void out_proj(
    const ushort_t* __restrict__ Oc,
    const ushort_t* __restrict__ Wb4,
    float* __restrict__ out)
{
  const int dims[7] = {1,1,2,2,2,2,2};
  const int rrb_[7] = {0,1,2,4,6,8,10};
  const int tile = blockIdx.x;
  int i = 0, t0 = 0;
  for (int k = 0; k < 7; ++k){
    int n = 128 * dims[k];
    if (tile >= t0 + n) t0 += n; else { i = k; break; }
  }
  const int d = dims[i], rrb = rrb_[i];
  const int w = threadIdx.x >> 6, lane = threadIdx.x & 63;
  const int lo = lane & 15, hi = lane >> 4;
  const int row0 = (tile - t0) * 64 + w * 16;

  bf16x8 afr[2];
  {
    int R  = row0 + lo;
    int bs = (d == 2) ? (R >> 1) : R;
    int dx = (d == 2) ? (R & 1)  : 0;
    const ushort_t* rp = Oc + (size_t)(bs*12 + rrb + dx) * 64;
    afr[0] = *(const bf16x8*)(rp + 8*hi);
    afr[1] = *(const bf16x8*)(rp + 32 + 8*hi);
  }
  const ushort_t* Wb = Wb4 + (size_t)3*28672 + (size_t)i * 64 * 64;
  #pragma unroll
  for (int ot = 0; ot < 4; ++ot){
    f32x4 acc = {0.f,0.f,0.f,0.f};
    #pragma unroll
    for (int c = 0; c < 2; ++c){
      bf16x8 bfr = *(const bf16x8*)(Wb + (size_t)(lo + 16*ot) * 64 + 32*c + 8*hi);
      acc = __builtin_amdgcn_mfma_f32_16x16x32_bf16(afr[c], bfr, acc, 0, 0, 0);
    }
    #pragma unroll
    for (int r = 0; r < 4; ++r){
      int R  = row0 + hi*4 + r;
      int bs = (d == 2) ? (R >> 1) : R;
      int dx = (d == 2) ? (R & 1)  : 0;
      out[(size_t)(bs*12 + rrb + dx) * 64 + lo + 16*ot] = acc[r];
    }
  }
}

extern "C" void kernel_launch(void* const* d_in, const int* in_sizes, int n_in,
                              void* d_out, int out_size, void* d_ws, size_t ws_size,
                              hipStream_t stream)
{
  const float* xA1 = (const float*)d_in[0];
  const float* xB2 = (const float*)d_in[1];
  const float* xE1 = (const float*)d_in[2];
  const float* xE2 = (const float*)d_in[3];
  const float* xE3 = (const float*)d_in[4];
  const float* xE4 = (const float*)d_in[5];
  const float* xE5 = (const float*)d_in[6];
  const float* Wq  = (const float*)d_in[7];
  const float* Wk  = (const float*)d_in[8];
  const float* Wv  = (const float*)d_in[9];
  const float* Wo  = (const float*)d_in[10];

  const size_t NE = (size_t)8 * 1024 * 12 * 64;   // 6,291,456
  ushort_t* Qg = (ushort_t*)d_ws;
  ushort_t* Kg = Qg + NE;
  ushort_t* Vg = Kg + NE;
  ushort_t* Oc = Vg + NE;
  ushort_t* Wb4 = Oc + NE;                        // 4*28672 bf16

  wconv<<<dim3(14,4), dim3(256), 0, stream>>>(Wq, Wk, Wv, Wo, Wb4);
  qkv_proj<<<dim3(1536), dim3(256), 0, stream>>>(xA1,xB2,xE1,xE2,xE3,xE4,xE5,
                                                 Wb4, Qg,Kg,Vg);
  attn<<<dim3(512), dim3(256), 0, stream>>>(Qg,Kg,Vg, Oc);
  out_proj<<<dim3(1536), dim3(256), 0, stream>>>(Oc, Wb4, (float*)d_out);
}